// Round 2
// baseline (1157.004 us; speedup 1.0000x reference)
//
#include <hip/hip_runtime.h>
#include <hip/hip_bf16.h>

// StructuredLinear (toeplitz_like, Stein displacement): y = x @ W
//   W[n,m] = p[(n-m)%N][m] - 0.5*c[(n-m)%N]
//   p[d][m] = sum_{j<=m} t[d][j],  c[d] = p[d][N-1]
//   t[d][j] = sum_r G[(d+j)%N][r] * H[j][r]
// N=4096, R=4, B=8192.
// Pipeline: build_T (fp32) -> gather W^T as bf16 hi/lo planes -> split x into
// bf16 hi/lo planes -> one MFMA GEMM accumulating x_hi*W_hi + x_hi*W_lo +
// x_lo*W_hi in fp32 (~1e-5 rel error vs fp32).

constexpr int N = 4096;
constexpr int BATCH = 8192;

typedef __attribute__((ext_vector_type(8))) short short8;
typedef __attribute__((ext_vector_type(4))) float f32x4;

// ---------------------------------------------------------------------------
// Kernel 1: per-diagonal prefix scan.  One workgroup per d (4096 blocks).
// T[d][m] = inclusive_prefix(t[d][.])[m] - 0.5 * total
// ---------------------------------------------------------------------------
__global__ __launch_bounds__(256) void build_T_kernel(const float* __restrict__ G,
                                                      const float* __restrict__ H,
                                                      float* __restrict__ T) {
    const int d = blockIdx.x;
    const int tid = threadIdx.x;
    const int j0 = tid * 16;

    float pref[16];
    float s = 0.f;
#pragma unroll
    for (int i = 0; i < 16; ++i) {
        const int j = j0 + i;
        const float4 g4 = *reinterpret_cast<const float4*>(G + (size_t)((d + j) & (N - 1)) * 4);
        const float4 h4 = *reinterpret_cast<const float4*>(H + (size_t)j * 4);
        s += g4.x * h4.x + g4.y * h4.y + g4.z * h4.z + g4.w * h4.w;
        pref[i] = s;  // inclusive within this thread's chunk
    }

    __shared__ float tot[256];
    tot[tid] = s;
    __syncthreads();
    for (int off = 1; off < 256; off <<= 1) {
        const float v = tot[tid];
        const float add = (tid >= off) ? tot[tid - off] : 0.f;
        __syncthreads();
        tot[tid] = v + add;
        __syncthreads();
    }
    const float total = tot[255];
    const float excl = (tid == 0) ? 0.f : tot[tid - 1];
    const float halfc = 0.5f * total;

    float* out = T + (size_t)d * N + j0;
#pragma unroll
    for (int i = 0; i < 16; ++i) out[i] = excl + pref[i] - halfc;
}

// ---------------------------------------------------------------------------
// Kernel 2a (bf16 path): gather W^T into bf16 hi/lo planes.
// Wt[m][n] = W[n][m] = T[(n-m)&(N-1)][m].  64x64 (m,n) tile per block.
// LDS pad +1 keeps the diagonal read phase conflict-free.
// ---------------------------------------------------------------------------
__global__ __launch_bounds__(256) void gather_Wt_bf16_kernel(const float* __restrict__ T,
                                                             __hip_bfloat16* __restrict__ Wh,
                                                             __hip_bfloat16* __restrict__ Wl) {
    __shared__ float tile[128][65];
    const int n0 = blockIdx.x * 64;
    const int m0 = blockIdx.y * 64;
    const int d0 = (n0 - m0 - 63) & (N - 1);
    const int t = threadIdx.x;

#pragma unroll
    for (int i = 0; i < 32; ++i) {
        const int flat = t + i * 256;   // 0..8191
        const int row = flat >> 6;      // d-local 0..127
        const int col = flat & 63;      // m-local
        tile[row][col] = T[(size_t)((d0 + row) & (N - 1)) * N + m0 + col];
    }
    __syncthreads();
#pragma unroll
    for (int i = 0; i < 16; ++i) {
        const int flat = t + i * 256;   // 0..4095
        const int lm = flat >> 6;       // m-local (row of Wt)
        const int ln = flat & 63;       // n-local (col of Wt, fast -> coalesced)
        const float w = tile[ln - lm + 63][lm];
        const __hip_bfloat16 h = __float2bfloat16(w);
        const __hip_bfloat16 l = __float2bfloat16(w - __bfloat162float(h));
        const size_t idx = (size_t)(m0 + lm) * N + n0 + ln;
        Wh[idx] = h;
        Wl[idx] = l;
    }
}

// ---------------------------------------------------------------------------
// Kernel 2b (fp32 fallback): gather W (row-major [n][m]) in fp32.
// ---------------------------------------------------------------------------
__global__ __launch_bounds__(256) void gather_W_kernel(const float* __restrict__ T,
                                                       float* __restrict__ W) {
    __shared__ float tile[128][64];
    const int m0 = blockIdx.x * 64;
    const int n0 = blockIdx.y * 64;
    const int d0 = (n0 - m0 - 63) & (N - 1);
    const int t = threadIdx.x;

#pragma unroll
    for (int i = 0; i < 32; ++i) {
        const int flat = t + i * 256;
        const int row = flat >> 6;
        const int col = flat & 63;
        tile[row][col] = T[(size_t)((d0 + row) & (N - 1)) * N + m0 + col];
    }
    __syncthreads();
#pragma unroll
    for (int i = 0; i < 16; ++i) {
        const int flat = t + i * 256;
        const int ln = flat >> 6;
        const int lm = flat & 63;
        W[(size_t)(n0 + ln) * N + m0 + lm] = tile[ln - lm + 63][lm];
    }
}

// ---------------------------------------------------------------------------
// Kernel 3: split x (fp32) into bf16 hi/lo planes.
// ---------------------------------------------------------------------------
__global__ __launch_bounds__(256) void split_x_kernel(const float* __restrict__ x,
                                                      __hip_bfloat16* __restrict__ xh,
                                                      __hip_bfloat16* __restrict__ xl) {
    const long long total8 = (long long)BATCH * N / 8;
    for (long long i = (long long)blockIdx.x * 256 + threadIdx.x; i < total8;
         i += (long long)gridDim.x * 256) {
        const float4 a = reinterpret_cast<const float4*>(x)[2 * i];
        const float4 b = reinterpret_cast<const float4*>(x)[2 * i + 1];
        const float v[8] = {a.x, a.y, a.z, a.w, b.x, b.y, b.z, b.w};
        short8 hv, lv;
#pragma unroll
        for (int j = 0; j < 8; ++j) {
            __hip_bfloat16 h = __float2bfloat16(v[j]);
            __hip_bfloat16 l = __float2bfloat16(v[j] - __bfloat162float(h));
            hv[j] = *reinterpret_cast<short*>(&h);
            lv[j] = *reinterpret_cast<short*>(&l);
        }
        *reinterpret_cast<short8*>(reinterpret_cast<short*>(xh) + i * 8) = hv;
        *reinterpret_cast<short8*>(reinterpret_cast<short*>(xl) + i * 8) = lv;
    }
}

// ---------------------------------------------------------------------------
// Kernel 4: split-bf16 MFMA GEMM.  C[8192][4096] = (xh+xl) @ (Wh+Wl)^T(stored
// as Wt row-major [m][k]).  m97 structure: 128x128 tile, BK=32, 4 waves,
// 16x16x32 bf16 MFMA, global_load_lds width 16, 2-barrier K-loop.
// 48 MFMA / K-step (hi*hi, hi*lo, lo*hi into one fp32 acc).
// ---------------------------------------------------------------------------
__device__ inline void gll16(const void* g, void* l) {
    __builtin_amdgcn_global_load_lds(
        (const __attribute__((address_space(1))) void*)g,
        (__attribute__((address_space(3))) void*)l, 16, 0, 0);
}

__global__ __launch_bounds__(256) void gemm_bf16_split_kernel(
    const short* __restrict__ xh, const short* __restrict__ xl,
    const short* __restrict__ wh, const short* __restrict__ wl,
    float* __restrict__ C) {
    __shared__ short Ah[128 * 32];
    __shared__ short Al[128 * 32];
    __shared__ short Bh[128 * 32];
    __shared__ short Bl[128 * 32];

    const int t = threadIdx.x;
    const int lane = t & 63;
    const int w = t >> 6;
    const int wm = w >> 1, wn = w & 1;          // 2x2 wave grid, 64x64 per wave
    const int bn0 = blockIdx.x * 128;
    const int bm0 = blockIdx.y * 128;
    const int lr = lane & 15;                   // fragment row/col
    const int lk = lane >> 4;                   // k-slice group 0..3

    f32x4 acc[4][4];
    const f32x4 zero = {0.f, 0.f, 0.f, 0.f};
#pragma unroll
    for (int i = 0; i < 4; ++i)
#pragma unroll
        for (int j = 0; j < 4; ++j) acc[i][j] = zero;

    for (int k0 = 0; k0 < N; k0 += 32) {
        __syncthreads();
#pragma unroll
        for (int i = 0; i < 2; ++i) {
            const int f = t + i * 256;          // 16B chunk id, 0..511
            const int row = f >> 2;             // tile row 0..127
            const int ko = (f & 3) << 3;        // k elem offset 0/8/16/24
            const size_t ga = (size_t)(bm0 + row) * N + k0 + ko;
            const size_t gb = (size_t)(bn0 + row) * N + k0 + ko;
            gll16(xh + ga, (char*)Ah + f * 16);
            gll16(xl + ga, (char*)Al + f * 16);
            gll16(wh + gb, (char*)Bh + f * 16);
            gll16(wl + gb, (char*)Bl + f * 16);
        }
        __syncthreads();

        short8 ah[4], al[4], bh[4], bl[4];
#pragma unroll
        for (int q = 0; q < 4; ++q) {
            const int ao = (wm * 64 + q * 16 + lr) * 32 + lk * 8;
            const int bo = (wn * 64 + q * 16 + lr) * 32 + lk * 8;
            ah[q] = *reinterpret_cast<const short8*>(&Ah[ao]);
            al[q] = *reinterpret_cast<const short8*>(&Al[ao]);
            bh[q] = *reinterpret_cast<const short8*>(&Bh[bo]);
            bl[q] = *reinterpret_cast<const short8*>(&Bl[bo]);
        }
#pragma unroll
        for (int mf = 0; mf < 4; ++mf)
#pragma unroll
            for (int nf = 0; nf < 4; ++nf) {
                acc[mf][nf] = __builtin_amdgcn_mfma_f32_16x16x32_bf16(ah[mf], bh[nf], acc[mf][nf], 0, 0, 0);
                acc[mf][nf] = __builtin_amdgcn_mfma_f32_16x16x32_bf16(ah[mf], bl[nf], acc[mf][nf], 0, 0, 0);
                acc[mf][nf] = __builtin_amdgcn_mfma_f32_16x16x32_bf16(al[mf], bh[nf], acc[mf][nf], 0, 0, 0);
            }
    }

    // C/D layout (m89-verified): col = lane&15, row = (lane>>4)*4 + reg
#pragma unroll
    for (int mf = 0; mf < 4; ++mf)
#pragma unroll
        for (int nf = 0; nf < 4; ++nf)
#pragma unroll
            for (int r = 0; r < 4; ++r)
                C[(size_t)(bm0 + wm * 64 + mf * 16 + lk * 4 + r) * N +
                  bn0 + wn * 64 + nf * 16 + lr] = acc[mf][nf][r];
}

// ---------------------------------------------------------------------------
// Kernel 5 (fp32 fallback GEMM), round-0 version.
// ---------------------------------------------------------------------------
__global__ __launch_bounds__(256) void gemm_f32_kernel(const float* __restrict__ A,
                                                       const float* __restrict__ B,
                                                       float* __restrict__ C) {
    __shared__ float As[16][132];
    __shared__ float Bs[16][128];

    const int t = threadIdx.x;
    const int bn0 = blockIdx.x * 128;
    const int bm0 = blockIdx.y * 128;
    const int tx = t & 15;
    const int ty = t >> 4;

    float acc[8][8] = {};

    for (int k0 = 0; k0 < N; k0 += 16) {
#pragma unroll
        for (int i = 0; i < 2; ++i) {
            const int flat4 = t + i * 256;
            const int r = flat4 >> 2;
            const int q = flat4 & 3;
            const float4 av =
                *reinterpret_cast<const float4*>(A + (size_t)(bm0 + r) * N + k0 + q * 4);
            As[q * 4 + 0][r] = av.x;
            As[q * 4 + 1][r] = av.y;
            As[q * 4 + 2][r] = av.z;
            As[q * 4 + 3][r] = av.w;
            const int rb = flat4 >> 5;
            const int qb = flat4 & 31;
            *reinterpret_cast<float4*>(&Bs[rb][qb * 4]) =
                *reinterpret_cast<const float4*>(B + (size_t)(k0 + rb) * N + bn0 + qb * 4);
        }
        __syncthreads();
#pragma unroll
        for (int k = 0; k < 16; ++k) {
            float a[8], b[8];
            *reinterpret_cast<float4*>(a)     = *reinterpret_cast<const float4*>(&As[k][ty * 8]);
            *reinterpret_cast<float4*>(a + 4) = *reinterpret_cast<const float4*>(&As[k][ty * 8 + 4]);
            *reinterpret_cast<float4*>(b)     = *reinterpret_cast<const float4*>(&Bs[k][tx * 8]);
            *reinterpret_cast<float4*>(b + 4) = *reinterpret_cast<const float4*>(&Bs[k][tx * 8 + 4]);
#pragma unroll
            for (int e = 0; e < 8; ++e)
#pragma unroll
                for (int f = 0; f < 8; ++f) acc[e][f] += a[e] * b[f];
        }
        __syncthreads();
    }

#pragma unroll
    for (int e = 0; e < 8; ++e) {
        float* crow = C + (size_t)(bm0 + ty * 8 + e) * N + bn0 + tx * 8;
        *reinterpret_cast<float4*>(crow)     = *reinterpret_cast<const float4*>(&acc[0] + e * 8);
        *reinterpret_cast<float4*>(crow + 4) = *reinterpret_cast<const float4*>(&acc[0] + e * 8 + 4);
    }
}

// ---------------------------------------------------------------------------
extern "C" void kernel_launch(void* const* d_in, const int* in_sizes, int n_in,
                              void* d_out, int out_size, void* d_ws, size_t ws_size,
                              hipStream_t stream) {
    const float* x = (const float*)d_in[0];  // (8192, 4096)
    const float* G = (const float*)d_in[1];  // (4096, 4)
    const float* H = (const float*)d_in[2];  // (4096, 4)
    float* out = (float*)d_out;              // (8192, 4096)

    char* ws = (char*)d_ws;
    const size_t SZ_T  = (size_t)N * N * sizeof(float);          // 64 MiB
    const size_t SZ_Wp = (size_t)N * N * 2;                      // 32 MiB bf16 plane
    const size_t SZ_Xp = (size_t)BATCH * N * 2;                  // 64 MiB bf16 plane

    float* T = nullptr;
    __hip_bfloat16 *Wh = nullptr, *Wl = nullptr, *Xh = nullptr, *Xl = nullptr;
    bool bf16_path = false;

    if (ws_size >= SZ_T + 2 * SZ_Wp + 2 * SZ_Xp) {               // 256 MiB
        T  = (float*)ws;
        Wh = (__hip_bfloat16*)(ws + SZ_T);
        Wl = (__hip_bfloat16*)(ws + SZ_T + SZ_Wp);
        Xh = (__hip_bfloat16*)(ws + SZ_T + 2 * SZ_Wp);
        Xl = (__hip_bfloat16*)(ws + SZ_T + 2 * SZ_Wp + SZ_Xp);
        bf16_path = true;
    } else if (ws_size >= 2 * SZ_Wp + 2 * SZ_Xp) {               // 192 MiB
        T  = (float*)d_out;  // consumed before the GEMM overwrites d_out
        Wh = (__hip_bfloat16*)ws;
        Wl = (__hip_bfloat16*)(ws + SZ_Wp);
        Xh = (__hip_bfloat16*)(ws + 2 * SZ_Wp);
        Xl = (__hip_bfloat16*)(ws + 2 * SZ_Wp + SZ_Xp);
        bf16_path = true;
    }

    if (bf16_path) {
        build_T_kernel<<<dim3(N), dim3(256), 0, stream>>>(G, H, T);
        gather_Wt_bf16_kernel<<<dim3(N / 64, N / 64), dim3(256), 0, stream>>>(T, Wh, Wl);
        split_x_kernel<<<dim3(2048), dim3(256), 0, stream>>>(x, Xh, Xl);
        gemm_bf16_split_kernel<<<dim3(N / 128, BATCH / 128), dim3(256), 0, stream>>>(
            (const short*)Xh, (const short*)Xl, (const short*)Wh, (const short*)Wl, out);
    } else {
        // fp32 fallback: T in d_out (overwritten by GEMM afterwards), W in ws.
        float* Tf = (float*)d_out;
        float* W  = (float*)ws;
        build_T_kernel<<<dim3(N), dim3(256), 0, stream>>>(G, H, Tf);
        gather_W_kernel<<<dim3(N / 64, N / 64), dim3(256), 0, stream>>>(Tf, W);
        gemm_f32_kernel<<<dim3(N / 128, BATCH / 128), dim3(256), 0, stream>>>(x, W, out);
    }
}